// Round 8
// baseline (1582.960 us; speedup 1.0000x reference)
//
#include <hip/hip_runtime.h>

#define T_STEPS 250
#define BATCH   256
#define IN_DIM  700
#define HID     1024
#define W_LD    1724   // = IN_DIM + HID
#define OUT_DIM 20
#define KP      704    // K padded to 22*32
#define KP4     (KP / 4)
#define NKT     (KP / 32)
#define CHUNK_T 50     // CUR chunk: 52 MB -> L3-resident, weights stay warm

typedef __attribute__((ext_vector_type(8))) short     bf16x8;
typedef __attribute__((ext_vector_type(8))) unsigned short u16x8;
typedef __attribute__((ext_vector_type(4))) float     f32x4;
typedef unsigned long long u64;

__device__ inline unsigned short f2bf(float f) {
    unsigned int u = __float_as_uint(f);
    unsigned int r = u + 0x7FFFu + ((u >> 16) & 1u);
    return (unsigned short)(r >> 16);
}

// ---------------------------------------------------------------------------
// WhhT_bf16[j][h] = bf16(W_h[h][700 + j]);  row 1024 is a zero sentinel row.
// ---------------------------------------------------------------------------
__global__ __launch_bounds__(256)
void trans_whh_bf16(const float* __restrict__ W_h, unsigned short* __restrict__ WhhT) {
    __shared__ float tile[32][33];
    const int bx = blockIdx.x * 32;  // h base
    const int by = blockIdx.y * 32;  // j base
    const int tx = threadIdx.x, ty = threadIdx.y;
#pragma unroll
    for (int i = 0; i < 32; i += 8)
        tile[ty + i][tx] = W_h[(size_t)(bx + ty + i) * W_LD + IN_DIM + by + tx];
    __syncthreads();
#pragma unroll
    for (int i = 0; i < 32; i += 8)
        WhhT[(size_t)(by + ty + i) * HID + bx + tx] = f2bf(tile[tx][ty + i]);
}

// WoT[h][o] = Wo[o][h]
__global__ __launch_bounds__(256)
void trans_wo(const float* __restrict__ Wo, float* __restrict__ WoT) {
    const int h = blockIdx.x * 256 + threadIdx.x;
    if (h >= HID) return;
#pragma unroll
    for (int o = 0; o < OUT_DIM; ++o)
        WoT[(size_t)h * OUT_DIM + o] = Wo[(size_t)o * HID + h];
}

// ---------------------------------------------------------------------------
// Pack x rows -> zero-padded K=704 bf16
// ---------------------------------------------------------------------------
__global__ __launch_bounds__(256)
void pack_x_bf16(const float* __restrict__ x, unsigned short* __restrict__ Xp, int rows) {
    const int total = rows * KP4;
    for (int idx = blockIdx.x * blockDim.x + threadIdx.x; idx < total;
         idx += gridDim.x * blockDim.x) {
        const int r = idx / KP4;
        const int c = idx - r * KP4;
        ushort4 o = make_ushort4(0, 0, 0, 0);
        if (c < IN_DIM / 4) {
            float4 v = *(const float4*)(x + (size_t)r * IN_DIM + c * 4);
            o = make_ushort4(f2bf(v.x), f2bf(v.y), f2bf(v.z), f2bf(v.w));
        }
        ((ushort4*)Xp)[(size_t)r * KP4 + c] = o;
    }
}

// Pack W_h's first 700 cols (ld 1724) -> [1024][704] bf16
__global__ __launch_bounds__(256)
void pack_w_bf16(const float* __restrict__ W_h, unsigned short* __restrict__ Wp) {
    const int total = HID * KP4;
    for (int idx = blockIdx.x * blockDim.x + threadIdx.x; idx < total;
         idx += gridDim.x * blockDim.x) {
        const int r = idx / KP4;
        const int c = idx - r * KP4;
        ushort4 o = make_ushort4(0, 0, 0, 0);
        if (c < IN_DIM / 4) {
            float4 v = *(const float4*)(W_h + (size_t)r * W_LD + c * 4);
            o = make_ushort4(f2bf(v.x), f2bf(v.y), f2bf(v.z), f2bf(v.w));
        }
        ((ushort4*)Wp)[(size_t)r * KP4 + c] = o;
    }
}

// ---------------------------------------------------------------------------
// bf16 MFMA GEMM: 128x128 tile, BK=32, 4 waves. (unchanged)
// ---------------------------------------------------------------------------
__global__ __launch_bounds__(256)
void mfma_gemm(const unsigned short* __restrict__ A,
               const unsigned short* __restrict__ B, float* __restrict__ C) {
    __shared__ unsigned short lA[128 * 32];
    __shared__ unsigned short lB[128 * 32];
    const int tid  = threadIdx.x;
    const int wid  = tid >> 6, lane = tid & 63;
    const int wr   = wid >> 1, wc = wid & 1;
    const size_t bm = (size_t)blockIdx.x * 128;
    const size_t bn = (size_t)blockIdx.y * 128;

    const int srow = tid >> 2;
    const int skq  = (tid & 3) * 8;

    const int wb0 = (srow * 64 + (tid & 3) * 16) ^ ((srow & 7) << 4);
    const int wb1 = ((srow + 64) * 64 + (tid & 3) * 16) ^ ((srow & 7) << 4);

    const unsigned short* pa = A + (bm + srow) * KP + skq;
    const unsigned short* pb = B + (bn + srow) * KP + skq;

    u16x8 ra0, ra1, rb0, rb1;
    auto ldg = [&](int k0) {
        ra0 = *(const u16x8*)(pa + k0);
        ra1 = *(const u16x8*)(pa + (size_t)64 * KP + k0);
        rb0 = *(const u16x8*)(pb + k0);
        rb1 = *(const u16x8*)(pb + (size_t)64 * KP + k0);
    };

    const int arow = wr * 64 + (lane & 15);
    const int brow = wc * 64 + (lane & 15);
    const int fq   = (lane >> 4) * 16;

    f32x4 acc[4][4];
#pragma unroll
    for (int m = 0; m < 4; ++m)
#pragma unroll
        for (int n = 0; n < 4; ++n) acc[m][n] = (f32x4){0.f, 0.f, 0.f, 0.f};

    ldg(0);
    for (int kt = 0; kt < NKT; ++kt) {
        *(u16x8*)((char*)lA + wb0) = ra0;
        *(u16x8*)((char*)lA + wb1) = ra1;
        *(u16x8*)((char*)lB + wb0) = rb0;
        *(u16x8*)((char*)lB + wb1) = rb1;
        __syncthreads();
        if (kt + 1 < NKT) ldg((kt + 1) * 32);
        bf16x8 af[4], bf[4];
#pragma unroll
        for (int m = 0; m < 4; ++m) {
            const int row = arow + m * 16;
            af[m] = *(const bf16x8*)((const char*)lA + ((row * 64 + fq) ^ ((row & 7) << 4)));
        }
#pragma unroll
        for (int n = 0; n < 4; ++n) {
            const int row = brow + n * 16;
            bf[n] = *(const bf16x8*)((const char*)lB + ((row * 64 + fq) ^ ((row & 7) << 4)));
        }
#pragma unroll
        for (int m = 0; m < 4; ++m)
#pragma unroll
            for (int n = 0; n < 4; ++n)
                acc[m][n] = __builtin_amdgcn_mfma_f32_16x16x32_bf16(af[m], bf[n], acc[m][n], 0, 0, 0);
        __syncthreads();
    }
#pragma unroll
    for (int m = 0; m < 4; ++m)
#pragma unroll
        for (int r = 0; r < 4; ++r) {
            float* cp = C + (bm + wr * 64 + m * 16 + (lane >> 4) * 4 + r) * HID
                          + bn + wc * 64 + (lane & 15);
#pragma unroll
            for (int n = 0; n < 4; ++n) cp[n * 16] = acc[m][n][r];
        }
}

// ---------------------------------------------------------------------------
// Persistent ALIF scan v6: 1 block = 1 wave = 1 batch, 16 neurons/lane.
// Depth-3 gather pipeline (A/B/C); xn (next-step CUR) issued AFTER the last
// gather load so in-order vmcnt retirement never stalls ACCUM on the CUR
// stream; numerics bit-identical to rounds 6/7 (same ops, same order).
// ---------------------------------------------------------------------------
#define LDIDX(JJ, g)                                                          \
    {                                                                         \
        const ushort4 i4 = *(const ushort4*)&s_idx[cur][(g) * 4];             \
        const int base_ = (g) * 4;                                            \
        JJ[0] = (base_ + 0 < n) ? (int)i4.x : 1024;                           \
        JJ[1] = (base_ + 1 < n) ? (int)i4.y : 1024;                           \
        JJ[2] = (base_ + 2 < n) ? (int)i4.z : 1024;                           \
        JJ[3] = (base_ + 3 < n) ? (int)i4.w : 1024;                           \
    }

#define ISSUE(WB, JJ)                                                         \
    {                                                                         \
        _Pragma("unroll")                                                     \
        for (int q_ = 0; q_ < 4; ++q_) {                                      \
            const unsigned int* p_ = Wrow32 + ((size_t)JJ[q_] << 9);          \
            WB[q_ * 2 + 0] = *(const uint4*)p_;                               \
            WB[q_ * 2 + 1] = *(const uint4*)(p_ + 4);                         \
        }                                                                     \
    }

#define ACCUM(WB)                                                             \
    {                                                                         \
        _Pragma("unroll")                                                     \
        for (int q_ = 0; q_ < 4; ++q_) {                                      \
            _Pragma("unroll")                                                 \
            for (int d_ = 0; d_ < 2; ++d_) {                                  \
                const uint4 w_ = WB[q_ * 2 + d_];                             \
                const int kb_ = d_ * 8;                                       \
                rec[kb_ + 0] += __uint_as_float(w_.x << 16);                  \
                rec[kb_ + 1] += __uint_as_float(w_.x & 0xFFFF0000u);          \
                rec[kb_ + 2] += __uint_as_float(w_.y << 16);                  \
                rec[kb_ + 3] += __uint_as_float(w_.y & 0xFFFF0000u);          \
                rec[kb_ + 4] += __uint_as_float(w_.z << 16);                  \
                rec[kb_ + 5] += __uint_as_float(w_.z & 0xFFFF0000u);          \
                rec[kb_ + 6] += __uint_as_float(w_.w << 16);                  \
                rec[kb_ + 7] += __uint_as_float(w_.w & 0xFFFF0000u);          \
            }                                                                 \
        }                                                                     \
    }

__global__ __launch_bounds__(64, 1)
void alif_scan(const float* __restrict__ CUR, const unsigned short* __restrict__ WhhT,
               const float* __restrict__ tau_mem, const float* __restrict__ tau_adp,
               float* __restrict__ zS, float* __restrict__ uS, float* __restrict__ aS,
               float* __restrict__ spkS, unsigned short* __restrict__ masks16,
               int t0, int tc) {
    const int b    = blockIdx.x;
    const int lane = threadIdx.x;      // 0..63
    const int h0   = lane * 16;

    __shared__ __align__(16) unsigned short s_idx[2][1040];

    float u[16], a[16], alpha[16], rho[16];
#pragma unroll
    for (int q = 0; q < 4; ++q) {
        f32x4 uu = *(const f32x4*)(uS + (size_t)b * HID + h0 + q * 4);
        f32x4 aa = *(const f32x4*)(aS + (size_t)b * HID + h0 + q * 4);
        f32x4 tm = *(const f32x4*)(tau_mem + h0 + q * 4);
        f32x4 ta = *(const f32x4*)(tau_adp + h0 + q * 4);
#pragma unroll
        for (int k = 0; k < 4; ++k) {
            u[q * 4 + k]     = uu[k];
            a[q * 4 + k]     = aa[k];
            alpha[q * 4 + k] = expf(-1.f / tm[k]);
            rho[q * 4 + k]   = expf(-1.f / ta[k]);
        }
    }
    unsigned int zb = 0;
#pragma unroll
    for (int q = 0; q < 4; ++q) {
        f32x4 zz = *(const f32x4*)(zS + (size_t)b * HID + h0 + q * 4);
#pragma unroll
        for (int k = 0; k < 4; ++k)
            if (zz[k] > 0.5f) zb |= (1u << (q * 4 + k));
    }

    // build initial spike list into buffer 0
    int n;
    {
        const int cnt = __popc(zb);
        int incl = cnt;
#pragma unroll
        for (int d = 1; d < 64; d <<= 1) {
            int v = __shfl_up(incl, d, 64);
            if (lane >= d) incl += v;
        }
        int off = incl - cnt;
        unsigned int tmp = zb;
        while (tmp) {
            const int k = __ffs(tmp) - 1;
            tmp &= tmp - 1;
            s_idx[0][off++] = (unsigned short)(h0 + k);
        }
        n = __shfl(incl, 63, 64);
    }

    const unsigned int* Wrow32 = (const unsigned int*)WhhT + (h0 >> 1);
    float xc[16];
#pragma unroll
    for (int q = 0; q < 4; ++q) {
        f32x4 v = *(const f32x4*)(CUR + (size_t)b * HID + h0 + q * 4);
        xc[q * 4 + 0] = v[0]; xc[q * 4 + 1] = v[1];
        xc[q * 4 + 2] = v[2]; xc[q * 4 + 3] = v[3];
    }
    __syncthreads();

    int cur = 0;
    int wspk = 0;
    for (int tt = 0; tt < tc; ++tt) {
        float rec[16];
#pragma unroll
        for (int k = 0; k < 16; ++k) rec[k] = 0.f;

        // ---- gather: depth-3 software pipeline, no CUR loads in front ----
        const int ng = (n + 3) >> 2;
        int  jA[4], jB[4], jC[4];
        uint4 wA[8], wB[8], wC[8];
        if (ng > 0) { LDIDX(jA, 0); ISSUE(wA, jA); }
        if (ng > 1) { LDIDX(jB, 1); ISSUE(wB, jB); }
        if (ng > 2) { LDIDX(jC, 2); ISSUE(wC, jC); }
        int g = 0;
        while (g < ng) {
            ACCUM(wA);
            if (g + 3 < ng) { LDIDX(jA, g + 3); ISSUE(wA, jA); }
            if (++g >= ng) break;
            ACCUM(wB);
            if (g + 3 < ng) { LDIDX(jB, g + 3); ISSUE(wB, jB); }
            if (++g >= ng) break;
            ACCUM(wC);
            if (g + 3 < ng) { LDIDX(jC, g + 3); ISSUE(wC, jC); }
            ++g;
        }

        // ---- neuron update (same expression tree as rounds 5-7) ----
        unsigned int znb = 0;
#pragma unroll
        for (int k = 0; k < 16; ++k) {
            const float z   = (zb >> k) & 1 ? 1.f : 0.f;
            const float omr = 1.f - rho[k];
            const float oma = 1.f - alpha[k];
            a[k] = rho[k] * a[k] + omr * z;
            const float th = 0.01f + 1.8f * a[k];
            u[k] = alpha[k] * u[k] + oma * (xc[k] + rec[k]) - z * th;
            if (u[k] - th > 0.f) znb |= (1u << k);
        }
        zb = znb;
        wspk += __popc(zb);

        // ---- NOW issue next step's CUR loads (after all gather loads) ----
        float xn[16];
        {
            const int tn = (tt + 1 < tc) ? tt + 1 : tt;
            const float* p = CUR + ((size_t)tn * BATCH + b) * HID + h0;
#pragma unroll
            for (int q = 0; q < 4; ++q) {
                f32x4 v = *(const f32x4*)(p + q * 4);
                xn[q * 4 + 0] = v[0]; xn[q * 4 + 1] = v[1];
                xn[q * 4 + 2] = v[2]; xn[q * 4 + 3] = v[3];
            }
        }

        masks16[((size_t)(t0 + tt) * BATCH + b) * 64 + lane] = (unsigned short)zb;

        // ---- build next spike list (covers xn latency) ----
        {
            const int cnt = __popc(zb);
            int incl = cnt;
#pragma unroll
            for (int d = 1; d < 64; d <<= 1) {
                int v = __shfl_up(incl, d, 64);
                if (lane >= d) incl += v;
            }
            int off = incl - cnt;
            unsigned int tmp = zb;
            while (tmp) {
                const int k = __ffs(tmp) - 1;
                tmp &= tmp - 1;
                s_idx[cur ^ 1][off++] = (unsigned short)(h0 + k);
            }
            n = __shfl(incl, 63, 64);
        }
#pragma unroll
        for (int k = 0; k < 16; ++k) xc[k] = xn[k];
        __syncthreads();   // single-wave: cheap; orders list writes vs reads
        cur ^= 1;
    }

    // write back state
#pragma unroll
    for (int k = 0; k < 16; ++k) {
        zS[(size_t)b * HID + h0 + k] = (zb >> k) & 1 ? 1.f : 0.f;
        uS[(size_t)b * HID + h0 + k] = u[k];
        aS[(size_t)b * HID + h0 + k] = a[k];
    }
#pragma unroll
    for (int d = 32; d > 0; d >>= 1) wspk += __shfl_down(wspk, d, 64);
    if (lane == 0) atomicAdd(spkS, (float)wspk);
}

// ---------------------------------------------------------------------------
// y[t*B+b][o] = sum over spiking j of WoT[j][o]  (one wave per (t,b) pair)
// ---------------------------------------------------------------------------
__global__ __launch_bounds__(256)
void readout_y(const u64* __restrict__ masks, const float* __restrict__ WoT,
               float* __restrict__ y, int npairs) {
    const int pr   = blockIdx.x * 4 + (threadIdx.x >> 6);
    const int lane = threadIdx.x & 63;
    if (pr >= npairs) return;
    const u64* mp = masks + (size_t)pr * 16;
    float acc = 0.f;
#pragma unroll 4
    for (int w = 0; w < 16; ++w) {
        u64 m = mp[w];
        while (m) {
            const int j = __ffsll((unsigned long long)m) - 1;
            m &= m - 1;
            if (lane < OUT_DIM) acc += WoT[(size_t)(w * 64 + j) * OUT_DIM + lane];
        }
    }
    if (lane < OUT_DIM) y[(size_t)pr * OUT_DIM + lane] = acc;
}

// ---------------------------------------------------------------------------
// outputs[t][b][o] = EWA over t of y; writes final ouT.
// ---------------------------------------------------------------------------
__global__ __launch_bounds__(256)
void ewa_out(const float* __restrict__ y, const float* __restrict__ tau_out,
             float* __restrict__ outputs, float* __restrict__ ouS) {
    const int idx = blockIdx.x * 256 + threadIdx.x;
    if (idx >= BATCH * OUT_DIM) return;
    const int o = idx % OUT_DIM;
    const float ao = expf(-1.f / tau_out[o]);
    float ou = ouS[idx];
    for (int t = 0; t < T_STEPS; ++t) {
        const float v = y[(size_t)t * BATCH * OUT_DIM + idx];
        ou = ao * ou + (1.f - ao) * v;
        outputs[(size_t)t * BATCH * OUT_DIM + idx] = ou;
    }
    ouS[idx] = ou;
}

// ---------------------------------------------------------------------------
extern "C" void kernel_launch(void* const* d_in, const int* in_sizes, int n_in,
                              void* d_out, int out_size, void* d_ws, size_t ws_size,
                              hipStream_t stream) {
    (void)in_sizes; (void)n_in; (void)out_size;
    const float* x       = (const float*)d_in[0];
    const float* W_h     = (const float*)d_in[1];
    const float* tau_mem = (const float*)d_in[2];
    const float* tau_adp = (const float*)d_in[3];
    const float* W_o     = (const float*)d_in[4];
    const float* tau_out = (const float*)d_in[5];

    float* out     = (float*)d_out;
    float* outputs = out;                                      // [250][256][20]
    float* zS  = out + (size_t)T_STEPS * BATCH * OUT_DIM;      // [256][1024]
    float* uS  = zS + (size_t)BATCH * HID;
    float* aS  = uS + (size_t)BATCH * HID;
    float* ouS = aS + (size_t)BATCH * HID;                     // [256][20]
    float* spk = ouS + (size_t)BATCH * OUT_DIM;                // scalar

    // ws layout (bytes)
    char* w = (char*)d_ws;
    unsigned short* WhhT = (unsigned short*)w; w += (size_t)(HID + 1) * HID * 2;  // 2 MB + zero row
    unsigned short* Wp   = (unsigned short*)w; w += (size_t)HID * KP * 2;         // 1.4 MB
    float*          WoT  = (float*)w;          w += (size_t)HID * OUT_DIM * 4;    // 80 KB
    unsigned short* masks16 = (unsigned short*)w; w += (size_t)T_STEPS * BATCH * 128; // 8 MB
    float*          yBuf = (float*)w;          w += (size_t)T_STEPS * BATCH * OUT_DIM * 4; // 5 MB
    char*           dynb = w;

    const size_t fixed = (size_t)(dynb - (char*)d_ws);
    const size_t per_step = (size_t)BATCH * KP * 2 + (size_t)BATCH * HID * 4;
    const size_t avail = ws_size > fixed ? ws_size - fixed : 0;
    int CT = (int)(avail / per_step);
    if (CT > CHUNK_T) CT = CHUNK_T;   // cap: keep chunk working set L3-resident
    if (CT < 1) CT = 1;

    hipMemsetAsync(zS, 0,
                   ((size_t)3 * BATCH * HID + BATCH * OUT_DIM + 1) * sizeof(float),
                   stream);
    hipMemsetAsync(WhhT + (size_t)HID * HID, 0, HID * sizeof(unsigned short), stream);
    trans_whh_bf16<<<dim3(32, 32), dim3(32, 8), 0, stream>>>(W_h, WhhT);
    pack_w_bf16<<<512, 256, 0, stream>>>(W_h, Wp);
    trans_wo<<<4, 256, 0, stream>>>(W_o, WoT);

    for (int t0 = 0; t0 < T_STEPS; t0 += CT) {
        const int tc = (T_STEPS - t0 < CT) ? (T_STEPS - t0) : CT;
        const int rows = tc * BATCH;
        unsigned short* Xp = (unsigned short*)dynb;
        float* CUR = (float*)(dynb + (size_t)rows * KP * 2);
        int pblocks = (rows * KP4 + 255) / 256;
        if (pblocks > 2048) pblocks = 2048;
        pack_x_bf16<<<pblocks, 256, 0, stream>>>(x + (size_t)t0 * BATCH * IN_DIM, Xp, rows);
        mfma_gemm<<<dim3(rows / 128, HID / 128), 256, 0, stream>>>(Xp, Wp, CUR);
        alif_scan<<<BATCH, 64, 0, stream>>>(CUR, WhhT, tau_mem, tau_adp,
                                            zS, uS, aS, spk, masks16, t0, tc);
    }

    const int npairs = T_STEPS * BATCH;
    readout_y<<<(npairs + 3) / 4, 256, 0, stream>>>((const u64*)masks16, WoT, yBuf, npairs);
    ewa_out<<<(BATCH * OUT_DIM + 255) / 256, 256, 0, stream>>>(yBuf, tau_out, outputs, ouS);
}

// Round 9
// 1471.982 us; speedup vs baseline: 1.0754x; 1.0754x over previous
//
#include <hip/hip_runtime.h>

#define T_STEPS 250
#define BATCH   256
#define IN_DIM  700
#define HID     1024
#define W_LD    1724   // = IN_DIM + HID
#define OUT_DIM 20
#define KP      704    // K padded to 22*32
#define KP4     (KP / 4)
#define NKT     (KP / 32)
#define CHUNK_T 50     // CUR chunk: 52 MB -> cache-resident (validated r8: FETCH 137->35MB)

typedef __attribute__((ext_vector_type(8))) short     bf16x8;
typedef __attribute__((ext_vector_type(8))) unsigned short u16x8;
typedef __attribute__((ext_vector_type(4))) float     f32x4;
typedef unsigned long long u64;

__device__ inline unsigned short f2bf(float f) {
    unsigned int u = __float_as_uint(f);
    unsigned int r = u + 0x7FFFu + ((u >> 16) & 1u);
    return (unsigned short)(r >> 16);
}

// ---------------------------------------------------------------------------
// WhhT_bf16[j][h] = bf16(W_h[h][700 + j]);  row 1024 is a zero sentinel row.
// ---------------------------------------------------------------------------
__global__ __launch_bounds__(256)
void trans_whh_bf16(const float* __restrict__ W_h, unsigned short* __restrict__ WhhT) {
    __shared__ float tile[32][33];
    const int bx = blockIdx.x * 32;  // h base
    const int by = blockIdx.y * 32;  // j base
    const int tx = threadIdx.x, ty = threadIdx.y;
#pragma unroll
    for (int i = 0; i < 32; i += 8)
        tile[ty + i][tx] = W_h[(size_t)(bx + ty + i) * W_LD + IN_DIM + by + tx];
    __syncthreads();
#pragma unroll
    for (int i = 0; i < 32; i += 8)
        WhhT[(size_t)(by + ty + i) * HID + bx + tx] = f2bf(tile[tx][ty + i]);
}

// Expand bf16 table (incl. zero row) to f32: Wf[i] = bf2f(Wb[i]), bit-exact.
__global__ __launch_bounds__(256)
void expand_whh_f32(const unsigned short* __restrict__ Wb, float* __restrict__ Wf) {
    const int idx = blockIdx.x * 256 + threadIdx.x;   // 8 elems/thread
    const int total8 = (HID + 1) * HID / 8;
    if (idx >= total8) return;
    u16x8 v = *(const u16x8*)(Wb + (size_t)idx * 8);
    float o[8];
#pragma unroll
    for (int k = 0; k < 8; ++k)
        o[k] = __uint_as_float(((unsigned int)(unsigned short)v[k]) << 16);
    *(f32x4*)(Wf + (size_t)idx * 8)     = (f32x4){o[0], o[1], o[2], o[3]};
    *(f32x4*)(Wf + (size_t)idx * 8 + 4) = (f32x4){o[4], o[5], o[6], o[7]};
}

// WoT[h][o] = Wo[o][h]
__global__ __launch_bounds__(256)
void trans_wo(const float* __restrict__ Wo, float* __restrict__ WoT) {
    const int h = blockIdx.x * 256 + threadIdx.x;
    if (h >= HID) return;
#pragma unroll
    for (int o = 0; o < OUT_DIM; ++o)
        WoT[(size_t)h * OUT_DIM + o] = Wo[(size_t)o * HID + h];
}

// ---------------------------------------------------------------------------
// Pack x rows -> zero-padded K=704 bf16
// ---------------------------------------------------------------------------
__global__ __launch_bounds__(256)
void pack_x_bf16(const float* __restrict__ x, unsigned short* __restrict__ Xp, int rows) {
    const int total = rows * KP4;
    for (int idx = blockIdx.x * blockDim.x + threadIdx.x; idx < total;
         idx += gridDim.x * blockDim.x) {
        const int r = idx / KP4;
        const int c = idx - r * KP4;
        ushort4 o = make_ushort4(0, 0, 0, 0);
        if (c < IN_DIM / 4) {
            float4 v = *(const float4*)(x + (size_t)r * IN_DIM + c * 4);
            o = make_ushort4(f2bf(v.x), f2bf(v.y), f2bf(v.z), f2bf(v.w));
        }
        ((ushort4*)Xp)[(size_t)r * KP4 + c] = o;
    }
}

// Pack W_h's first 700 cols (ld 1724) -> [1024][704] bf16
__global__ __launch_bounds__(256)
void pack_w_bf16(const float* __restrict__ W_h, unsigned short* __restrict__ Wp) {
    const int total = HID * KP4;
    for (int idx = blockIdx.x * blockDim.x + threadIdx.x; idx < total;
         idx += gridDim.x * blockDim.x) {
        const int r = idx / KP4;
        const int c = idx - r * KP4;
        ushort4 o = make_ushort4(0, 0, 0, 0);
        if (c < IN_DIM / 4) {
            float4 v = *(const float4*)(W_h + (size_t)r * W_LD + c * 4);
            o = make_ushort4(f2bf(v.x), f2bf(v.y), f2bf(v.z), f2bf(v.w));
        }
        ((ushort4*)Wp)[(size_t)r * KP4 + c] = o;
    }
}

// ---------------------------------------------------------------------------
// bf16 MFMA GEMM: 128x128 tile, BK=32, 4 waves. (unchanged)
// ---------------------------------------------------------------------------
__global__ __launch_bounds__(256)
void mfma_gemm(const unsigned short* __restrict__ A,
               const unsigned short* __restrict__ B, float* __restrict__ C) {
    __shared__ unsigned short lA[128 * 32];
    __shared__ unsigned short lB[128 * 32];
    const int tid  = threadIdx.x;
    const int wid  = tid >> 6, lane = tid & 63;
    const int wr   = wid >> 1, wc = wid & 1;
    const size_t bm = (size_t)blockIdx.x * 128;
    const size_t bn = (size_t)blockIdx.y * 128;

    const int srow = tid >> 2;
    const int skq  = (tid & 3) * 8;

    const int wb0 = (srow * 64 + (tid & 3) * 16) ^ ((srow & 7) << 4);
    const int wb1 = ((srow + 64) * 64 + (tid & 3) * 16) ^ ((srow & 7) << 4);

    const unsigned short* pa = A + (bm + srow) * KP + skq;
    const unsigned short* pb = B + (bn + srow) * KP + skq;

    u16x8 ra0, ra1, rb0, rb1;
    auto ldg = [&](int k0) {
        ra0 = *(const u16x8*)(pa + k0);
        ra1 = *(const u16x8*)(pa + (size_t)64 * KP + k0);
        rb0 = *(const u16x8*)(pb + k0);
        rb1 = *(const u16x8*)(pb + (size_t)64 * KP + k0);
    };

    const int arow = wr * 64 + (lane & 15);
    const int brow = wc * 64 + (lane & 15);
    const int fq   = (lane >> 4) * 16;

    f32x4 acc[4][4];
#pragma unroll
    for (int m = 0; m < 4; ++m)
#pragma unroll
        for (int n = 0; n < 4; ++n) acc[m][n] = (f32x4){0.f, 0.f, 0.f, 0.f};

    ldg(0);
    for (int kt = 0; kt < NKT; ++kt) {
        *(u16x8*)((char*)lA + wb0) = ra0;
        *(u16x8*)((char*)lA + wb1) = ra1;
        *(u16x8*)((char*)lB + wb0) = rb0;
        *(u16x8*)((char*)lB + wb1) = rb1;
        __syncthreads();
        if (kt + 1 < NKT) ldg((kt + 1) * 32);
        bf16x8 af[4], bf[4];
#pragma unroll
        for (int m = 0; m < 4; ++m) {
            const int row = arow + m * 16;
            af[m] = *(const bf16x8*)((const char*)lA + ((row * 64 + fq) ^ ((row & 7) << 4)));
        }
#pragma unroll
        for (int n = 0; n < 4; ++n) {
            const int row = brow + n * 16;
            bf[n] = *(const bf16x8*)((const char*)lB + ((row * 64 + fq) ^ ((row & 7) << 4)));
        }
#pragma unroll
        for (int m = 0; m < 4; ++m)
#pragma unroll
            for (int n = 0; n < 4; ++n)
                acc[m][n] = __builtin_amdgcn_mfma_f32_16x16x32_bf16(af[m], bf[n], acc[m][n], 0, 0, 0);
        __syncthreads();
    }
#pragma unroll
    for (int m = 0; m < 4; ++m)
#pragma unroll
        for (int r = 0; r < 4; ++r) {
            float* cp = C + (bm + wr * 64 + m * 16 + (lane >> 4) * 4 + r) * HID
                          + bn + wc * 64 + (lane & 15);
#pragma unroll
            for (int n = 0; n < 4; ++n) cp[n * 16] = acc[m][n][r];
        }
}

// ===========================================================================
// A/B scan variants. Both: 1 block = 1 wave = 1 batch, 16 neurons/lane,
// bit-identical trajectory (ascending-j sum order, identical f32 addends).
// ===========================================================================

// ---- arm A: r5-exact gather (bf16 table, depth-2, 4-spike groups, xn top) --
#define A_LDIDX(JJ, g)                                                        \
    {                                                                         \
        const ushort4 i4 = *(const ushort4*)&s_idx[cur][(g) * 4];             \
        const int base_ = (g) * 4;                                            \
        JJ[0] = (base_ + 0 < n) ? (int)i4.x : 1024;                           \
        JJ[1] = (base_ + 1 < n) ? (int)i4.y : 1024;                           \
        JJ[2] = (base_ + 2 < n) ? (int)i4.z : 1024;                           \
        JJ[3] = (base_ + 3 < n) ? (int)i4.w : 1024;                           \
    }

#define A_ISSUE(WB, JJ)                                                       \
    {                                                                         \
        _Pragma("unroll")                                                     \
        for (int q_ = 0; q_ < 4; ++q_) {                                      \
            const unsigned int* p_ = Wrow32 + ((size_t)JJ[q_] << 9);          \
            WB[q_ * 2 + 0] = *(const uint4*)p_;                               \
            WB[q_ * 2 + 1] = *(const uint4*)(p_ + 4);                         \
        }                                                                     \
    }

#define A_ACCUM(WB)                                                           \
    {                                                                         \
        _Pragma("unroll")                                                     \
        for (int q_ = 0; q_ < 4; ++q_) {                                      \
            _Pragma("unroll")                                                 \
            for (int d_ = 0; d_ < 2; ++d_) {                                  \
                const uint4 w_ = WB[q_ * 2 + d_];                             \
                const int kb_ = d_ * 8;                                       \
                rec[kb_ + 0] += __uint_as_float(w_.x << 16);                  \
                rec[kb_ + 1] += __uint_as_float(w_.x & 0xFFFF0000u);          \
                rec[kb_ + 2] += __uint_as_float(w_.y << 16);                  \
                rec[kb_ + 3] += __uint_as_float(w_.y & 0xFFFF0000u);          \
                rec[kb_ + 4] += __uint_as_float(w_.z << 16);                  \
                rec[kb_ + 5] += __uint_as_float(w_.z & 0xFFFF0000u);          \
                rec[kb_ + 6] += __uint_as_float(w_.w << 16);                  \
                rec[kb_ + 7] += __uint_as_float(w_.w & 0xFFFF0000u);          \
            }                                                                 \
        }                                                                     \
    }

__global__ __launch_bounds__(64, 1)
void alif_scan_a(const float* __restrict__ CUR, const unsigned short* __restrict__ WhhT,
                 const float* __restrict__ tau_mem, const float* __restrict__ tau_adp,
                 float* __restrict__ zS, float* __restrict__ uS, float* __restrict__ aS,
                 float* __restrict__ spkS, unsigned short* __restrict__ masks16,
                 int t0, int tc) {
    const int b    = blockIdx.x;
    const int lane = threadIdx.x;
    const int h0   = lane * 16;

    __shared__ __align__(16) unsigned short s_idx[2][1040];

    float u[16], a[16], alpha[16], rho[16];
#pragma unroll
    for (int q = 0; q < 4; ++q) {
        f32x4 uu = *(const f32x4*)(uS + (size_t)b * HID + h0 + q * 4);
        f32x4 aa = *(const f32x4*)(aS + (size_t)b * HID + h0 + q * 4);
        f32x4 tm = *(const f32x4*)(tau_mem + h0 + q * 4);
        f32x4 ta = *(const f32x4*)(tau_adp + h0 + q * 4);
#pragma unroll
        for (int k = 0; k < 4; ++k) {
            u[q * 4 + k] = uu[k];  a[q * 4 + k] = aa[k];
            alpha[q * 4 + k] = expf(-1.f / tm[k]);
            rho[q * 4 + k]   = expf(-1.f / ta[k]);
        }
    }
    unsigned int zb = 0;
#pragma unroll
    for (int q = 0; q < 4; ++q) {
        f32x4 zz = *(const f32x4*)(zS + (size_t)b * HID + h0 + q * 4);
#pragma unroll
        for (int k = 0; k < 4; ++k)
            if (zz[k] > 0.5f) zb |= (1u << (q * 4 + k));
    }

    int n;
    {
        const int cnt = __popc(zb);
        int incl = cnt;
#pragma unroll
        for (int d = 1; d < 64; d <<= 1) {
            int v = __shfl_up(incl, d, 64);
            if (lane >= d) incl += v;
        }
        int off = incl - cnt;
        unsigned int tmp = zb;
        while (tmp) {
            const int k = __ffs(tmp) - 1;
            tmp &= tmp - 1;
            s_idx[0][off++] = (unsigned short)(h0 + k);
        }
        n = __shfl(incl, 63, 64);
    }

    const unsigned int* Wrow32 = (const unsigned int*)WhhT + (h0 >> 1);
    float xc[16];
#pragma unroll
    for (int q = 0; q < 4; ++q) {
        f32x4 v = *(const f32x4*)(CUR + (size_t)b * HID + h0 + q * 4);
        xc[q*4+0]=v[0]; xc[q*4+1]=v[1]; xc[q*4+2]=v[2]; xc[q*4+3]=v[3];
    }
    __syncthreads();

    int cur = 0;
    int wspk = 0;
    for (int tt = 0; tt < tc; ++tt) {
        float xn[16];
        {
            const int tn = (tt + 1 < tc) ? tt + 1 : tt;
            const float* p = CUR + ((size_t)tn * BATCH + b) * HID + h0;
#pragma unroll
            for (int q = 0; q < 4; ++q) {
                f32x4 v = *(const f32x4*)(p + q * 4);
                xn[q*4+0]=v[0]; xn[q*4+1]=v[1]; xn[q*4+2]=v[2]; xn[q*4+3]=v[3];
            }
        }

        float rec[16];
#pragma unroll
        for (int k = 0; k < 16; ++k) rec[k] = 0.f;

        if (n > 0) {
            const int ng = (n + 3) >> 2;
            int  jA[4], jB[4];
            uint4 wA[8], wB[8];
            A_LDIDX(jA, 0);
            A_ISSUE(wA, jA);
            int g = 0;
            while (true) {
                if (g + 1 < ng) { A_LDIDX(jB, g + 1); A_ISSUE(wB, jB); }
                A_ACCUM(wA);
                if (++g >= ng) break;
                if (g + 1 < ng) { A_LDIDX(jA, g + 1); A_ISSUE(wA, jA); }
                A_ACCUM(wB);
                if (++g >= ng) break;
            }
        }

        unsigned int znb = 0;
#pragma unroll
        for (int k = 0; k < 16; ++k) {
            const float z   = (zb >> k) & 1 ? 1.f : 0.f;
            const float omr = 1.f - rho[k];
            const float oma = 1.f - alpha[k];
            a[k] = rho[k] * a[k] + omr * z;
            const float th = 0.01f + 1.8f * a[k];
            u[k] = alpha[k] * u[k] + oma * (xc[k] + rec[k]) - z * th;
            if (u[k] - th > 0.f) znb |= (1u << k);
        }
        zb = znb;
        wspk += __popc(zb);
        masks16[((size_t)(t0 + tt) * BATCH + b) * 64 + lane] = (unsigned short)zb;

        {
            const int cnt = __popc(zb);
            int incl = cnt;
#pragma unroll
            for (int d = 1; d < 64; d <<= 1) {
                int v = __shfl_up(incl, d, 64);
                if (lane >= d) incl += v;
            }
            int off = incl - cnt;
            unsigned int tmp = zb;
            while (tmp) {
                const int k = __ffs(tmp) - 1;
                tmp &= tmp - 1;
                s_idx[cur ^ 1][off++] = (unsigned short)(h0 + k);
            }
            n = __shfl(incl, 63, 64);
        }
#pragma unroll
        for (int k = 0; k < 16; ++k) xc[k] = xn[k];
        __syncthreads();
        cur ^= 1;
    }

#pragma unroll
    for (int k = 0; k < 16; ++k) {
        zS[(size_t)b * HID + h0 + k] = (zb >> k) & 1 ? 1.f : 0.f;
        uS[(size_t)b * HID + h0 + k] = u[k];
        aS[(size_t)b * HID + h0 + k] = a[k];
    }
#pragma unroll
    for (int d = 32; d > 0; d >>= 1) wspk += __shfl_down(wspk, d, 64);
    if (lane == 0) atomicAdd(spkS, (float)wspk);
}

// ---- arm B: f32 table (zero unpack ALU), depth-2, 2-spike groups, xn top ---
#define B_LDIDX(JJ, g)                                                        \
    {                                                                         \
        const ushort2 i2 = *(const ushort2*)&s_idx[cur][(g) * 2];             \
        const int base_ = (g) * 2;                                            \
        JJ[0] = (base_ + 0 < n) ? (int)i2.x : 1024;                           \
        JJ[1] = (base_ + 1 < n) ? (int)i2.y : 1024;                           \
    }

#define B_ISSUE(WB, JJ)                                                       \
    {                                                                         \
        _Pragma("unroll")                                                     \
        for (int s_ = 0; s_ < 2; ++s_) {                                      \
            const f32x4* p_ = (const f32x4*)(WfRow + ((size_t)JJ[s_] << 10)); \
            WB[s_ * 4 + 0] = p_[0];                                           \
            WB[s_ * 4 + 1] = p_[1];                                           \
            WB[s_ * 4 + 2] = p_[2];                                           \
            WB[s_ * 4 + 3] = p_[3];                                           \
        }                                                                     \
    }

#define B_ACCUM(WB)                                                           \
    {                                                                         \
        _Pragma("unroll")                                                     \
        for (int s_ = 0; s_ < 2; ++s_) {                                      \
            _Pragma("unroll")                                                 \
            for (int r_ = 0; r_ < 4; ++r_) {                                  \
                rec[r_ * 4 + 0] += WB[s_ * 4 + r_][0];                        \
                rec[r_ * 4 + 1] += WB[s_ * 4 + r_][1];                        \
                rec[r_ * 4 + 2] += WB[s_ * 4 + r_][2];                        \
                rec[r_ * 4 + 3] += WB[s_ * 4 + r_][3];                        \
            }                                                                 \
        }                                                                     \
    }

__global__ __launch_bounds__(64, 1)
void alif_scan_b(const float* __restrict__ CUR, const float* __restrict__ Wf,
                 const float* __restrict__ tau_mem, const float* __restrict__ tau_adp,
                 float* __restrict__ zS, float* __restrict__ uS, float* __restrict__ aS,
                 float* __restrict__ spkS, unsigned short* __restrict__ masks16,
                 int t0, int tc) {
    const int b    = blockIdx.x;
    const int lane = threadIdx.x;
    const int h0   = lane * 16;

    __shared__ __align__(16) unsigned short s_idx[2][1040];

    float u[16], a[16], alpha[16], rho[16];
#pragma unroll
    for (int q = 0; q < 4; ++q) {
        f32x4 uu = *(const f32x4*)(uS + (size_t)b * HID + h0 + q * 4);
        f32x4 aa = *(const f32x4*)(aS + (size_t)b * HID + h0 + q * 4);
        f32x4 tm = *(const f32x4*)(tau_mem + h0 + q * 4);
        f32x4 ta = *(const f32x4*)(tau_adp + h0 + q * 4);
#pragma unroll
        for (int k = 0; k < 4; ++k) {
            u[q * 4 + k] = uu[k];  a[q * 4 + k] = aa[k];
            alpha[q * 4 + k] = expf(-1.f / tm[k]);
            rho[q * 4 + k]   = expf(-1.f / ta[k]);
        }
    }
    unsigned int zb = 0;
#pragma unroll
    for (int q = 0; q < 4; ++q) {
        f32x4 zz = *(const f32x4*)(zS + (size_t)b * HID + h0 + q * 4);
#pragma unroll
        for (int k = 0; k < 4; ++k)
            if (zz[k] > 0.5f) zb |= (1u << (q * 4 + k));
    }

    int n;
    {
        const int cnt = __popc(zb);
        int incl = cnt;
#pragma unroll
        for (int d = 1; d < 64; d <<= 1) {
            int v = __shfl_up(incl, d, 64);
            if (lane >= d) incl += v;
        }
        int off = incl - cnt;
        unsigned int tmp = zb;
        while (tmp) {
            const int k = __ffs(tmp) - 1;
            tmp &= tmp - 1;
            s_idx[0][off++] = (unsigned short)(h0 + k);
        }
        n = __shfl(incl, 63, 64);
    }

    const float* WfRow = Wf + h0;
    float xc[16];
#pragma unroll
    for (int q = 0; q < 4; ++q) {
        f32x4 v = *(const f32x4*)(CUR + (size_t)b * HID + h0 + q * 4);
        xc[q*4+0]=v[0]; xc[q*4+1]=v[1]; xc[q*4+2]=v[2]; xc[q*4+3]=v[3];
    }
    __syncthreads();

    int cur = 0;
    int wspk = 0;
    for (int tt = 0; tt < tc; ++tt) {
        float xn[16];
        {
            const int tn = (tt + 1 < tc) ? tt + 1 : tt;
            const float* p = CUR + ((size_t)tn * BATCH + b) * HID + h0;
#pragma unroll
            for (int q = 0; q < 4; ++q) {
                f32x4 v = *(const f32x4*)(p + q * 4);
                xn[q*4+0]=v[0]; xn[q*4+1]=v[1]; xn[q*4+2]=v[2]; xn[q*4+3]=v[3];
            }
        }

        float rec[16];
#pragma unroll
        for (int k = 0; k < 16; ++k) rec[k] = 0.f;

        if (n > 0) {
            const int ng = (n + 1) >> 1;
            int   jA[2], jB[2];
            f32x4 wA[8], wB[8];
            B_LDIDX(jA, 0);
            B_ISSUE(wA, jA);
            int g = 0;
            while (true) {
                if (g + 1 < ng) { B_LDIDX(jB, g + 1); B_ISSUE(wB, jB); }
                B_ACCUM(wA);
                if (++g >= ng) break;
                if (g + 1 < ng) { B_LDIDX(jA, g + 1); B_ISSUE(wA, jA); }
                B_ACCUM(wB);
                if (++g >= ng) break;
            }
        }

        unsigned int znb = 0;
#pragma unroll
        for (int k = 0; k < 16; ++k) {
            const float z   = (zb >> k) & 1 ? 1.f : 0.f;
            const float omr = 1.f - rho[k];
            const float oma = 1.f - alpha[k];
            a[k] = rho[k] * a[k] + omr * z;
            const float th = 0.01f + 1.8f * a[k];
            u[k] = alpha[k] * u[k] + oma * (xc[k] + rec[k]) - z * th;
            if (u[k] - th > 0.f) znb |= (1u << k);
        }
        zb = znb;
        wspk += __popc(zb);
        masks16[((size_t)(t0 + tt) * BATCH + b) * 64 + lane] = (unsigned short)zb;

        {
            const int cnt = __popc(zb);
            int incl = cnt;
#pragma unroll
            for (int d = 1; d < 64; d <<= 1) {
                int v = __shfl_up(incl, d, 64);
                if (lane >= d) incl += v;
            }
            int off = incl - cnt;
            unsigned int tmp = zb;
            while (tmp) {
                const int k = __ffs(tmp) - 1;
                tmp &= tmp - 1;
                s_idx[cur ^ 1][off++] = (unsigned short)(h0 + k);
            }
            n = __shfl(incl, 63, 64);
        }
#pragma unroll
        for (int k = 0; k < 16; ++k) xc[k] = xn[k];
        __syncthreads();
        cur ^= 1;
    }

#pragma unroll
    for (int k = 0; k < 16; ++k) {
        zS[(size_t)b * HID + h0 + k] = (zb >> k) & 1 ? 1.f : 0.f;
        uS[(size_t)b * HID + h0 + k] = u[k];
        aS[(size_t)b * HID + h0 + k] = a[k];
    }
#pragma unroll
    for (int d = 32; d > 0; d >>= 1) wspk += __shfl_down(wspk, d, 64);
    if (lane == 0) atomicAdd(spkS, (float)wspk);
}

// ---------------------------------------------------------------------------
// y[t*B+b][o] = sum over spiking j of WoT[j][o]  (one wave per (t,b) pair)
// ---------------------------------------------------------------------------
__global__ __launch_bounds__(256)
void readout_y(const u64* __restrict__ masks, const float* __restrict__ WoT,
               float* __restrict__ y, int npairs) {
    const int pr   = blockIdx.x * 4 + (threadIdx.x >> 6);
    const int lane = threadIdx.x & 63;
    if (pr >= npairs) return;
    const u64* mp = masks + (size_t)pr * 16;
    float acc = 0.f;
#pragma unroll 4
    for (int w = 0; w < 16; ++w) {
        u64 m = mp[w];
        while (m) {
            const int j = __ffsll((unsigned long long)m) - 1;
            m &= m - 1;
            if (lane < OUT_DIM) acc += WoT[(size_t)(w * 64 + j) * OUT_DIM + lane];
        }
    }
    if (lane < OUT_DIM) y[(size_t)pr * OUT_DIM + lane] = acc;
}

// ---------------------------------------------------------------------------
// outputs[t][b][o] = EWA over t of y; writes final ouT.
// ---------------------------------------------------------------------------
__global__ __launch_bounds__(256)
void ewa_out(const float* __restrict__ y, const float* __restrict__ tau_out,
             float* __restrict__ outputs, float* __restrict__ ouS) {
    const int idx = blockIdx.x * 256 + threadIdx.x;
    if (idx >= BATCH * OUT_DIM) return;
    const int o = idx % OUT_DIM;
    const float ao = expf(-1.f / tau_out[o]);
    float ou = ouS[idx];
    for (int t = 0; t < T_STEPS; ++t) {
        const float v = y[(size_t)t * BATCH * OUT_DIM + idx];
        ou = ao * ou + (1.f - ao) * v;
        outputs[(size_t)t * BATCH * OUT_DIM + idx] = ou;
    }
    ouS[idx] = ou;
}

// ---------------------------------------------------------------------------
extern "C" void kernel_launch(void* const* d_in, const int* in_sizes, int n_in,
                              void* d_out, int out_size, void* d_ws, size_t ws_size,
                              hipStream_t stream) {
    (void)in_sizes; (void)n_in; (void)out_size;
    const float* x       = (const float*)d_in[0];
    const float* W_h     = (const float*)d_in[1];
    const float* tau_mem = (const float*)d_in[2];
    const float* tau_adp = (const float*)d_in[3];
    const float* W_o     = (const float*)d_in[4];
    const float* tau_out = (const float*)d_in[5];

    float* out     = (float*)d_out;
    float* outputs = out;                                      // [250][256][20]
    float* zS  = out + (size_t)T_STEPS * BATCH * OUT_DIM;      // [256][1024]
    float* uS  = zS + (size_t)BATCH * HID;
    float* aS  = uS + (size_t)BATCH * HID;
    float* ouS = aS + (size_t)BATCH * HID;                     // [256][20]
    float* spk = ouS + (size_t)BATCH * OUT_DIM;                // scalar

    // ws layout (bytes)
    char* w = (char*)d_ws;
    unsigned short* WhhT = (unsigned short*)w; w += (size_t)(HID + 1) * HID * 2;  // 2 MB + zero row
    float*          Wf   = (float*)w;          w += (size_t)(HID + 1) * HID * 4;  // 4 MB + zero row
    unsigned short* Wp   = (unsigned short*)w; w += (size_t)HID * KP * 2;         // 1.4 MB
    float*          WoT  = (float*)w;          w += (size_t)HID * OUT_DIM * 4;    // 80 KB
    unsigned short* masks16 = (unsigned short*)w; w += (size_t)T_STEPS * BATCH * 128; // 8 MB
    float*          yBuf = (float*)w;          w += (size_t)T_STEPS * BATCH * OUT_DIM * 4; // 5 MB
    char*           dynb = w;

    const size_t fixed = (size_t)(dynb - (char*)d_ws);
    const size_t per_step = (size_t)BATCH * KP * 2 + (size_t)BATCH * HID * 4;
    const size_t avail = ws_size > fixed ? ws_size - fixed : 0;
    int CT = (int)(avail / per_step);
    if (CT > CHUNK_T) CT = CHUNK_T;
    if (CT < 1) CT = 1;

    hipMemsetAsync(zS, 0,
                   ((size_t)3 * BATCH * HID + BATCH * OUT_DIM + 1) * sizeof(float),
                   stream);
    hipMemsetAsync(WhhT + (size_t)HID * HID, 0, HID * sizeof(unsigned short), stream);
    trans_whh_bf16<<<dim3(32, 32), dim3(32, 8), 0, stream>>>(W_h, WhhT);
    expand_whh_f32<<<((HID + 1) * HID / 8 + 255) / 256, 256, 0, stream>>>(WhhT, Wf);
    pack_w_bf16<<<512, 256, 0, stream>>>(W_h, Wp);
    trans_wo<<<4, 256, 0, stream>>>(W_o, WoT);

    int chunk = 0;
    for (int t0 = 0; t0 < T_STEPS; t0 += CT, ++chunk) {
        const int tc = (T_STEPS - t0 < CT) ? (T_STEPS - t0) : CT;
        const int rows = tc * BATCH;
        unsigned short* Xp = (unsigned short*)dynb;
        float* CUR = (float*)(dynb + (size_t)rows * KP * 2);
        int pblocks = (rows * KP4 + 255) / 256;
        if (pblocks > 2048) pblocks = 2048;
        pack_x_bf16<<<pblocks, 256, 0, stream>>>(x + (size_t)t0 * BATCH * IN_DIM, Xp, rows);
        mfma_gemm<<<dim3(rows / 128, HID / 128), 256, 0, stream>>>(Xp, Wp, CUR);
        if (chunk & 1)
            alif_scan_b<<<BATCH, 64, 0, stream>>>(CUR, Wf, tau_mem, tau_adp,
                                                  zS, uS, aS, spk, masks16, t0, tc);
        else
            alif_scan_a<<<BATCH, 64, 0, stream>>>(CUR, WhhT, tau_mem, tau_adp,
                                                  zS, uS, aS, spk, masks16, t0, tc);
    }

    const int npairs = T_STEPS * BATCH;
    readout_y<<<(npairs + 3) / 4, 256, 0, stream>>>((const u64*)masks16, WoT, yBuf, npairs);
    ewa_out<<<(BATCH * OUT_DIM + 255) / 256, 256, 0, stream>>>(yBuf, tau_out, outputs, ouS);
}

// Round 10
// 1050.078 us; speedup vs baseline: 1.5075x; 1.4018x over previous
//
#include <hip/hip_runtime.h>

#define T_STEPS 250
#define BATCH   256
#define IN_DIM  700
#define HID     1024
#define W_LD    1724   // = IN_DIM + HID
#define OUT_DIM 20
#define KP      704    // K padded to 22*32
#define KP4     (KP / 4)
#define NKT     (KP / 32)
#define CHUNK_T 50     // CUR chunk: 52 MB -> cache-resident (r8: FETCH 137->35MB)

typedef __attribute__((ext_vector_type(8))) short     bf16x8;
typedef __attribute__((ext_vector_type(8))) unsigned short u16x8;
typedef __attribute__((ext_vector_type(4))) float     f32x4;
typedef unsigned long long u64;

__device__ inline unsigned short f2bf(float f) {
    unsigned int u = __float_as_uint(f);
    unsigned int r = u + 0x7FFFu + ((u >> 16) & 1u);
    return (unsigned short)(r >> 16);
}

// ---------------------------------------------------------------------------
// WhhT_bf16[j][h] = bf16(W_h[h][700 + j]);  row 1024 is a zero sentinel row.
// ---------------------------------------------------------------------------
__global__ __launch_bounds__(256)
void trans_whh_bf16(const float* __restrict__ W_h, unsigned short* __restrict__ WhhT) {
    __shared__ float tile[32][33];
    const int bx = blockIdx.x * 32;  // h base
    const int by = blockIdx.y * 32;  // j base
    const int tx = threadIdx.x, ty = threadIdx.y;
#pragma unroll
    for (int i = 0; i < 32; i += 8)
        tile[ty + i][tx] = W_h[(size_t)(bx + ty + i) * W_LD + IN_DIM + by + tx];
    __syncthreads();
#pragma unroll
    for (int i = 0; i < 32; i += 8)
        WhhT[(size_t)(by + ty + i) * HID + bx + tx] = f2bf(tile[tx][ty + i]);
}

// WoT[h][o] = Wo[o][h]
__global__ __launch_bounds__(256)
void trans_wo(const float* __restrict__ Wo, float* __restrict__ WoT) {
    const int h = blockIdx.x * 256 + threadIdx.x;
    if (h >= HID) return;
#pragma unroll
    for (int o = 0; o < OUT_DIM; ++o)
        WoT[(size_t)h * OUT_DIM + o] = Wo[(size_t)o * HID + h];
}

// ---------------------------------------------------------------------------
// Pack x rows -> zero-padded K=704 bf16
// ---------------------------------------------------------------------------
__global__ __launch_bounds__(256)
void pack_x_bf16(const float* __restrict__ x, unsigned short* __restrict__ Xp, int rows) {
    const int total = rows * KP4;
    for (int idx = blockIdx.x * blockDim.x + threadIdx.x; idx < total;
         idx += gridDim.x * blockDim.x) {
        const int r = idx / KP4;
        const int c = idx - r * KP4;
        ushort4 o = make_ushort4(0, 0, 0, 0);
        if (c < IN_DIM / 4) {
            float4 v = *(const float4*)(x + (size_t)r * IN_DIM + c * 4);
            o = make_ushort4(f2bf(v.x), f2bf(v.y), f2bf(v.z), f2bf(v.w));
        }
        ((ushort4*)Xp)[(size_t)r * KP4 + c] = o;
    }
}

// Pack W_h's first 700 cols (ld 1724) -> [1024][704] bf16
__global__ __launch_bounds__(256)
void pack_w_bf16(const float* __restrict__ W_h, unsigned short* __restrict__ Wp) {
    const int total = HID * KP4;
    for (int idx = blockIdx.x * blockDim.x + threadIdx.x; idx < total;
         idx += gridDim.x * blockDim.x) {
        const int r = idx / KP4;
        const int c = idx - r * KP4;
        ushort4 o = make_ushort4(0, 0, 0, 0);
        if (c < IN_DIM / 4) {
            float4 v = *(const float4*)(W_h + (size_t)r * W_LD + c * 4);
            o = make_ushort4(f2bf(v.x), f2bf(v.y), f2bf(v.z), f2bf(v.w));
        }
        ((ushort4*)Wp)[(size_t)r * KP4 + c] = o;
    }
}

// ---------------------------------------------------------------------------
// bf16 MFMA GEMM: 128x128 tile, BK=32, 4 waves. (unchanged)
// ---------------------------------------------------------------------------
__global__ __launch_bounds__(256)
void mfma_gemm(const unsigned short* __restrict__ A,
               const unsigned short* __restrict__ B, float* __restrict__ C) {
    __shared__ unsigned short lA[128 * 32];
    __shared__ unsigned short lB[128 * 32];
    const int tid  = threadIdx.x;
    const int wid  = tid >> 6, lane = tid & 63;
    const int wr   = wid >> 1, wc = wid & 1;
    const size_t bm = (size_t)blockIdx.x * 128;
    const size_t bn = (size_t)blockIdx.y * 128;

    const int srow = tid >> 2;
    const int skq  = (tid & 3) * 8;

    const int wb0 = (srow * 64 + (tid & 3) * 16) ^ ((srow & 7) << 4);
    const int wb1 = ((srow + 64) * 64 + (tid & 3) * 16) ^ ((srow & 7) << 4);

    const unsigned short* pa = A + (bm + srow) * KP + skq;
    const unsigned short* pb = B + (bn + srow) * KP + skq;

    u16x8 ra0, ra1, rb0, rb1;
    auto ldg = [&](int k0) {
        ra0 = *(const u16x8*)(pa + k0);
        ra1 = *(const u16x8*)(pa + (size_t)64 * KP + k0);
        rb0 = *(const u16x8*)(pb + k0);
        rb1 = *(const u16x8*)(pb + (size_t)64 * KP + k0);
    };

    const int arow = wr * 64 + (lane & 15);
    const int brow = wc * 64 + (lane & 15);
    const int fq   = (lane >> 4) * 16;

    f32x4 acc[4][4];
#pragma unroll
    for (int m = 0; m < 4; ++m)
#pragma unroll
        for (int n = 0; n < 4; ++n) acc[m][n] = (f32x4){0.f, 0.f, 0.f, 0.f};

    ldg(0);
    for (int kt = 0; kt < NKT; ++kt) {
        *(u16x8*)((char*)lA + wb0) = ra0;
        *(u16x8*)((char*)lA + wb1) = ra1;
        *(u16x8*)((char*)lB + wb0) = rb0;
        *(u16x8*)((char*)lB + wb1) = rb1;
        __syncthreads();
        if (kt + 1 < NKT) ldg((kt + 1) * 32);
        bf16x8 af[4], bf[4];
#pragma unroll
        for (int m = 0; m < 4; ++m) {
            const int row = arow + m * 16;
            af[m] = *(const bf16x8*)((const char*)lA + ((row * 64 + fq) ^ ((row & 7) << 4)));
        }
#pragma unroll
        for (int n = 0; n < 4; ++n) {
            const int row = brow + n * 16;
            bf[n] = *(const bf16x8*)((const char*)lB + ((row * 64 + fq) ^ ((row & 7) << 4)));
        }
#pragma unroll
        for (int m = 0; m < 4; ++m)
#pragma unroll
            for (int n = 0; n < 4; ++n)
                acc[m][n] = __builtin_amdgcn_mfma_f32_16x16x32_bf16(af[m], bf[n], acc[m][n], 0, 0, 0);
        __syncthreads();
    }
#pragma unroll
    for (int m = 0; m < 4; ++m)
#pragma unroll
        for (int r = 0; r < 4; ++r) {
            float* cp = C + (bm + wr * 64 + m * 16 + (lane >> 4) * 4 + r) * HID
                          + bn + wc * 64 + (lane & 15);
#pragma unroll
            for (int n = 0; n < 4; ++n) cp[n * 16] = acc[m][n][r];
        }
}

// ---------------------------------------------------------------------------
// Persistent ALIF scan v7: 1 block = 1 batch, 4 WAVES, 16 neurons/lane.
// Spike list split in quarters ACROSS WAVES (4x fewer gather loads per lane,
// 4x the load-issuing waves). Partials exchanged via conflict-free LDS
// (f32x4 lane-contiguous), summed in fixed wave order. Update replicated
// identically in all waves (deterministic). bf16 table (r9 A/B winner).
// ---------------------------------------------------------------------------
#define G_LDIDX(JJ, g)                                                        \
    {                                                                         \
        const int base_ = lo + (g) * 4;                                       \
        JJ[0] = (base_ + 0 < hi) ? (int)lst[base_ + 0] : 1024;                \
        JJ[1] = (base_ + 1 < hi) ? (int)lst[base_ + 1] : 1024;                \
        JJ[2] = (base_ + 2 < hi) ? (int)lst[base_ + 2] : 1024;                \
        JJ[3] = (base_ + 3 < hi) ? (int)lst[base_ + 3] : 1024;                \
    }

#define G_ISSUE(WB, JJ)                                                       \
    {                                                                         \
        _Pragma("unroll")                                                     \
        for (int q_ = 0; q_ < 4; ++q_) {                                      \
            const unsigned int* p_ = Wrow32 + ((size_t)JJ[q_] << 9);          \
            WB[q_ * 2 + 0] = *(const uint4*)p_;                               \
            WB[q_ * 2 + 1] = *(const uint4*)(p_ + 4);                         \
        }                                                                     \
    }

#define G_ACCUM(WB)                                                           \
    {                                                                         \
        _Pragma("unroll")                                                     \
        for (int q_ = 0; q_ < 4; ++q_) {                                      \
            const uint4 w0_ = WB[q_ * 2 + 0];                                 \
            const uint4 w1_ = WB[q_ * 2 + 1];                                 \
            pacc[0][0] += __uint_as_float(w0_.x << 16);                       \
            pacc[0][1] += __uint_as_float(w0_.x & 0xFFFF0000u);               \
            pacc[0][2] += __uint_as_float(w0_.y << 16);                       \
            pacc[0][3] += __uint_as_float(w0_.y & 0xFFFF0000u);               \
            pacc[1][0] += __uint_as_float(w0_.z << 16);                       \
            pacc[1][1] += __uint_as_float(w0_.z & 0xFFFF0000u);               \
            pacc[1][2] += __uint_as_float(w0_.w << 16);                       \
            pacc[1][3] += __uint_as_float(w0_.w & 0xFFFF0000u);               \
            pacc[2][0] += __uint_as_float(w1_.x << 16);                       \
            pacc[2][1] += __uint_as_float(w1_.x & 0xFFFF0000u);               \
            pacc[2][2] += __uint_as_float(w1_.y << 16);                       \
            pacc[2][3] += __uint_as_float(w1_.y & 0xFFFF0000u);               \
            pacc[3][0] += __uint_as_float(w1_.z << 16);                       \
            pacc[3][1] += __uint_as_float(w1_.z & 0xFFFF0000u);               \
            pacc[3][2] += __uint_as_float(w1_.w << 16);                       \
            pacc[3][3] += __uint_as_float(w1_.w & 0xFFFF0000u);               \
        }                                                                     \
    }

__global__ __launch_bounds__(256, 1)
void alif_scan(const float* __restrict__ CUR, const unsigned short* __restrict__ WhhT,
               const float* __restrict__ tau_mem, const float* __restrict__ tau_adp,
               float* __restrict__ zS, float* __restrict__ uS, float* __restrict__ aS,
               float* __restrict__ spkS, unsigned short* __restrict__ masks16,
               int t0, int tc) {
    const int tid  = threadIdx.x;
    const int wv   = tid >> 6;         // wave 0..3
    const int lane = tid & 63;
    const int b    = blockIdx.x;
    const int h0   = lane * 16;

    __shared__ __align__(16) unsigned short s_idx[4][2][1040];  // per-wave lists
    __shared__ __align__(16) f32x4 s_part[4][4][64];            // [wave][q][lane]

    // --- state: replicated identically in every wave ---
    float u[16], a[16], alpha[16], rho[16];
#pragma unroll
    for (int q = 0; q < 4; ++q) {
        f32x4 uu = *(const f32x4*)(uS + (size_t)b * HID + h0 + q * 4);
        f32x4 aa = *(const f32x4*)(aS + (size_t)b * HID + h0 + q * 4);
        f32x4 tm = *(const f32x4*)(tau_mem + h0 + q * 4);
        f32x4 ta = *(const f32x4*)(tau_adp + h0 + q * 4);
#pragma unroll
        for (int k = 0; k < 4; ++k) {
            u[q * 4 + k] = uu[k];  a[q * 4 + k] = aa[k];
            alpha[q * 4 + k] = expf(-1.f / tm[k]);
            rho[q * 4 + k]   = expf(-1.f / ta[k]);
        }
    }
    unsigned int zb = 0;
#pragma unroll
    for (int q = 0; q < 4; ++q) {
        f32x4 zz = *(const f32x4*)(zS + (size_t)b * HID + h0 + q * 4);
#pragma unroll
        for (int k = 0; k < 4; ++k)
            if (zz[k] > 0.5f) zb |= (1u << (q * 4 + k));
    }

    // build initial list into own-wave buffer 0 (identical content per wave)
    int n;
    {
        const int cnt = __popc(zb);
        int incl = cnt;
#pragma unroll
        for (int d = 1; d < 64; d <<= 1) {
            int v = __shfl_up(incl, d, 64);
            if (lane >= d) incl += v;
        }
        int off = incl - cnt;
        unsigned int tmp = zb;
        while (tmp) {
            const int k = __ffs(tmp) - 1;
            tmp &= tmp - 1;
            s_idx[wv][0][off++] = (unsigned short)(h0 + k);
        }
        n = __shfl(incl, 63, 64);
    }

    const unsigned int* Wrow32 = (const unsigned int*)WhhT + (h0 >> 1);
    float xc[16];
#pragma unroll
    for (int q = 0; q < 4; ++q) {
        f32x4 v = *(const f32x4*)(CUR + (size_t)b * HID + h0 + q * 4);
        xc[q*4+0]=v[0]; xc[q*4+1]=v[1]; xc[q*4+2]=v[2]; xc[q*4+3]=v[3];
    }
    __syncthreads();

    int cur = 0;
    int wspk = 0;
    for (int tt = 0; tt < tc; ++tt) {
        // prefetch next step's input current (cache-resident chunk)
        float xn[16];
        {
            const int tn = (tt + 1 < tc) ? tt + 1 : tt;
            const float* p = CUR + ((size_t)tn * BATCH + b) * HID + h0;
#pragma unroll
            for (int q = 0; q < 4; ++q) {
                f32x4 v = *(const f32x4*)(p + q * 4);
                xn[q*4+0]=v[0]; xn[q*4+1]=v[1]; xn[q*4+2]=v[2]; xn[q*4+3]=v[3];
            }
        }

        f32x4 pacc[4];
#pragma unroll
        for (int q = 0; q < 4; ++q) pacc[q] = (f32x4){0.f, 0.f, 0.f, 0.f};

        if (n > 0) {
            // --- this wave gathers its quarter of the spike list ---
            const unsigned short* lst = s_idx[wv][cur];
            const int lo = (n * wv) >> 2;
            const int hi = (n * (wv + 1)) >> 2;
            const int m = hi - lo;
            if (m > 0) {
                const int ng = (m + 3) >> 2;
                int  jA[4], jB[4];
                uint4 wA[8], wB[8];
                G_LDIDX(jA, 0);
                G_ISSUE(wA, jA);
                int g = 0;
                while (true) {
                    if (g + 1 < ng) { G_LDIDX(jB, g + 1); G_ISSUE(wB, jB); }
                    G_ACCUM(wA);
                    if (++g >= ng) break;
                    if (g + 1 < ng) { G_LDIDX(jA, g + 1); G_ISSUE(wA, jA); }
                    G_ACCUM(wB);
                    if (++g >= ng) break;
                }
            }
            // --- exchange partials (conflict-free: lane-contiguous f32x4) ---
            s_part[wv][0][lane] = pacc[0];
            s_part[wv][1][lane] = pacc[1];
            s_part[wv][2][lane] = pacc[2];
            s_part[wv][3][lane] = pacc[3];
            __syncthreads();
#pragma unroll
            for (int q = 0; q < 4; ++q) {
                f32x4 r0 = s_part[0][q][lane];
                f32x4 r1 = s_part[1][q][lane];
                f32x4 r2 = s_part[2][q][lane];
                f32x4 r3 = s_part[3][q][lane];
                pacc[q] = ((r0 + r1) + r2) + r3;   // fixed wave order
            }
        }

        // --- neuron update: replicated identically in all 4 waves ---
        unsigned int znb = 0;
#pragma unroll
        for (int k = 0; k < 16; ++k) {
            const float rec = pacc[k >> 2][k & 3];
            const float z   = (zb >> k) & 1 ? 1.f : 0.f;
            const float omr = 1.f - rho[k];
            const float oma = 1.f - alpha[k];
            a[k] = rho[k] * a[k] + omr * z;
            const float th = 0.01f + 1.8f * a[k];
            u[k] = alpha[k] * u[k] + oma * (xc[k] + rec) - z * th;
            if (u[k] - th > 0.f) znb |= (1u << k);
        }
        zb = znb;
        wspk += __popc(zb);
        if (wv == 0)
            masks16[((size_t)(t0 + tt) * BATCH + b) * 64 + lane] = (unsigned short)zb;

        // --- each wave builds its own (identical) next list ---
        {
            const int cnt = __popc(zb);
            int incl = cnt;
#pragma unroll
            for (int d = 1; d < 64; d <<= 1) {
                int v = __shfl_up(incl, d, 64);
                if (lane >= d) incl += v;
            }
            int off = incl - cnt;
            unsigned int tmp = zb;
            while (tmp) {
                const int k = __ffs(tmp) - 1;
                tmp &= tmp - 1;
                s_idx[wv][cur ^ 1][off++] = (unsigned short)(h0 + k);
            }
            n = __shfl(incl, 63, 64);
        }
#pragma unroll
        for (int k = 0; k < 16; ++k) xc[k] = xn[k];
        __syncthreads();   // end of step: orders s_part reads vs next writes
        cur ^= 1;
    }

    // write back state (wave 0 only — all waves identical)
    if (wv == 0) {
#pragma unroll
        for (int k = 0; k < 16; ++k) {
            zS[(size_t)b * HID + h0 + k] = (zb >> k) & 1 ? 1.f : 0.f;
            uS[(size_t)b * HID + h0 + k] = u[k];
            aS[(size_t)b * HID + h0 + k] = a[k];
        }
#pragma unroll
        for (int d = 32; d > 0; d >>= 1) wspk += __shfl_down(wspk, d, 64);
        if (lane == 0) atomicAdd(spkS, (float)wspk);
    }
}

// ---------------------------------------------------------------------------
// y[t*B+b][o] = sum over spiking j of WoT[j][o]  (one wave per (t,b) pair)
// ---------------------------------------------------------------------------
__global__ __launch_bounds__(256)
void readout_y(const u64* __restrict__ masks, const float* __restrict__ WoT,
               float* __restrict__ y, int npairs) {
    const int pr   = blockIdx.x * 4 + (threadIdx.x >> 6);
    const int lane = threadIdx.x & 63;
    if (pr >= npairs) return;
    const u64* mp = masks + (size_t)pr * 16;
    float acc = 0.f;
#pragma unroll 4
    for (int w = 0; w < 16; ++w) {
        u64 m = mp[w];
        while (m) {
            const int j = __ffsll((unsigned long long)m) - 1;
            m &= m - 1;
            if (lane < OUT_DIM) acc += WoT[(size_t)(w * 64 + j) * OUT_DIM + lane];
        }
    }
    if (lane < OUT_DIM) y[(size_t)pr * OUT_DIM + lane] = acc;
}

// ---------------------------------------------------------------------------
// outputs[t][b][o] = EWA over t of y; writes final ouT.
// ---------------------------------------------------------------------------
__global__ __launch_bounds__(256)
void ewa_out(const float* __restrict__ y, const float* __restrict__ tau_out,
             float* __restrict__ outputs, float* __restrict__ ouS) {
    const int idx = blockIdx.x * 256 + threadIdx.x;
    if (idx >= BATCH * OUT_DIM) return;
    const int o = idx % OUT_DIM;
    const float ao = expf(-1.f / tau_out[o]);
    float ou = ouS[idx];
    for (int t = 0; t < T_STEPS; ++t) {
        const float v = y[(size_t)t * BATCH * OUT_DIM + idx];
        ou = ao * ou + (1.f - ao) * v;
        outputs[(size_t)t * BATCH * OUT_DIM + idx] = ou;
    }
    ouS[idx] = ou;
}

// ---------------------------------------------------------------------------
extern "C" void kernel_launch(void* const* d_in, const int* in_sizes, int n_in,
                              void* d_out, int out_size, void* d_ws, size_t ws_size,
                              hipStream_t stream) {
    (void)in_sizes; (void)n_in; (void)out_size;
    const float* x       = (const float*)d_in[0];
    const float* W_h     = (const float*)d_in[1];
    const float* tau_mem = (const float*)d_in[2];
    const float* tau_adp = (const float*)d_in[3];
    const float* W_o     = (const float*)d_in[4];
    const float* tau_out = (const float*)d_in[5];

    float* out     = (float*)d_out;
    float* outputs = out;                                      // [250][256][20]
    float* zS  = out + (size_t)T_STEPS * BATCH * OUT_DIM;      // [256][1024]
    float* uS  = zS + (size_t)BATCH * HID;
    float* aS  = uS + (size_t)BATCH * HID;
    float* ouS = aS + (size_t)BATCH * HID;                     // [256][20]
    float* spk = ouS + (size_t)BATCH * OUT_DIM;                // scalar

    // ws layout (bytes)
    char* w = (char*)d_ws;
    unsigned short* WhhT = (unsigned short*)w; w += (size_t)(HID + 1) * HID * 2;  // 2 MB + zero row
    unsigned short* Wp   = (unsigned short*)w; w += (size_t)HID * KP * 2;         // 1.4 MB
    float*          WoT  = (float*)w;          w += (size_t)HID * OUT_DIM * 4;    // 80 KB
    unsigned short* masks16 = (unsigned short*)w; w += (size_t)T_STEPS * BATCH * 128; // 8 MB
    float*          yBuf = (float*)w;          w += (size_t)T_STEPS * BATCH * OUT_DIM * 4; // 5 MB
    char*           dynb = w;

    const size_t fixed = (size_t)(dynb - (char*)d_ws);
    const size_t per_step = (size_t)BATCH * KP * 2 + (size_t)BATCH * HID * 4;
    const size_t avail = ws_size > fixed ? ws_size - fixed : 0;
    int CT = (int)(avail / per_step);
    if (CT > CHUNK_T) CT = CHUNK_T;
    if (CT < 1) CT = 1;

    hipMemsetAsync(zS, 0,
                   ((size_t)3 * BATCH * HID + BATCH * OUT_DIM + 1) * sizeof(float),
                   stream);
    hipMemsetAsync(WhhT + (size_t)HID * HID, 0, HID * sizeof(unsigned short), stream);
    trans_whh_bf16<<<dim3(32, 32), dim3(32, 8), 0, stream>>>(W_h, WhhT);
    pack_w_bf16<<<512, 256, 0, stream>>>(W_h, Wp);
    trans_wo<<<4, 256, 0, stream>>>(W_o, WoT);

    for (int t0 = 0; t0 < T_STEPS; t0 += CT) {
        const int tc = (T_STEPS - t0 < CT) ? (T_STEPS - t0) : CT;
        const int rows = tc * BATCH;
        unsigned short* Xp = (unsigned short*)dynb;
        float* CUR = (float*)(dynb + (size_t)rows * KP * 2);
        int pblocks = (rows * KP4 + 255) / 256;
        if (pblocks > 2048) pblocks = 2048;
        pack_x_bf16<<<pblocks, 256, 0, stream>>>(x + (size_t)t0 * BATCH * IN_DIM, Xp, rows);
        mfma_gemm<<<dim3(rows / 128, HID / 128), 256, 0, stream>>>(Xp, Wp, CUR);
        alif_scan<<<BATCH, 256, 0, stream>>>(CUR, WhhT, tau_mem, tau_adp,
                                             zS, uS, aS, spk, masks16, t0, tc);
    }

    const int npairs = T_STEPS * BATCH;
    readout_y<<<(npairs + 3) / 4, 256, 0, stream>>>((const u64*)masks16, WoT, yBuf, npairs);
    ewa_out<<<(BATCH * OUT_DIM + 255) / 256, 256, 0, stream>>>(yBuf, tau_out, outputs, ouS);
}